// Round 7
// baseline (95.727 us; speedup 1.0000x reference)
//
#include <hip/hip_runtime.h>
#include <math.h>

typedef unsigned short u16;
typedef u16 u16x4 __attribute__((ext_vector_type(4)));
typedef u16 u16x8 __attribute__((ext_vector_type(8)));
typedef float f32x4 __attribute__((ext_vector_type(4)));
typedef float f32x16 __attribute__((ext_vector_type(16)));
typedef __bf16 bf16x8 __attribute__((ext_vector_type(8)));

#define KC 8
#define K2L 2304  // 256*9

__device__ __forceinline__ u16 f2bf_rne(float f) {
  unsigned u = __float_as_uint(f);
  u += 0x7FFFu + ((u >> 16) & 1u);
  return (u16)(u >> 16);
}
__device__ __forceinline__ float bf2f(u16 h) {
  return __uint_as_float(((unsigned)h) << 16);
}

// async global->LDS, 16B/lane; LDS dest is the WAVE-UNIFORM base (HW adds lane*16)
__device__ __forceinline__ void gload16(const u16* g, u16* l) {
  __builtin_amdgcn_global_load_lds(
      (const __attribute__((address_space(1))) unsigned*)g,
      (__attribute__((address_space(3))) unsigned*)l, 16, 0, 0);
}

// ---- merged prep: split x, split W1, build Wc1, Wc2 ----
__device__ __forceinline__ void split4(const float* X, u16* hi, u16* lo, int i) {
  f32x4 v = ((const f32x4*)X)[i];
  u16x4 h, l;
#pragma unroll
  for (int c = 0; c < 4; ++c) {
    u16 hb = f2bf_rne(v[c]);
    h[c] = hb;
    l[c] = f2bf_rne(v[c] - bf2f(hb));
  }
  ((u16x4*)hi)[i] = h;
  ((u16x4*)lo)[i] = l;
}
__device__ __forceinline__ void wc_one(const float* coef, const float* sb, const float* sp,
                                       const float* mask, u16* W, int N, int idx) {
  int o = idx / K2L;
  int r = idx - o * K2L;
  int i = r / 9;
  int c = r - i * 9;
  int io = i * N + o;
  float m = mask[io];
  float v = (c == 0) ? m * sb[io] : m * sp[io] * coef[(size_t)io * KC + (c - 1)];
  W[idx] = f2bf_rne(v);
}

__global__ void prep_kernel(const float* __restrict__ x, const float* __restrict__ W1,
                            const float* __restrict__ coef1, const float* __restrict__ sb1,
                            const float* __restrict__ sp1, const float* __restrict__ mask1,
                            const float* __restrict__ coef2, const float* __restrict__ sb2,
                            const float* __restrict__ sp2, const float* __restrict__ mask2,
                            u16* __restrict__ xs_hi, u16* __restrict__ xs_lo,
                            u16* __restrict__ w1_hi, u16* __restrict__ w1_lo,
                            u16* __restrict__ wc1, u16* __restrict__ wc2) {
  const int b = blockIdx.x, tid = threadIdx.x;
  if (b < 4096) {                       // split x
    split4(x, xs_hi, xs_lo, b * 256 + tid);
  } else if (b < 4096 + 256) {          // split W1
    split4(W1, w1_hi, w1_lo, (b - 4096) * 256 + tid);
  } else if (b < 4096 + 256 + 2304) {   // Wc1
    wc_one(coef1, sb1, sp1, mask1, wc1, 256, (b - 4352) * 256 + tid);
  } else {                              // Wc2
    wc_one(coef2, sb2, sp2, mask2, wc2, 128, (b - 6656) * 256 + tid);
  }
}

// ---- spline tables + divide-free expand ----
struct Spl {
  float g[12];
  float d1[11], d2[10], d3[9];
};
__device__ __forceinline__ void spl_init(const float* __restrict__ grid, Spl& sp) {
#pragma unroll
  for (int j = 0; j < 12; ++j) sp.g[j] = grid[j];
#pragma unroll
  for (int j = 0; j < 11; ++j) sp.d1[j] = 1.0f / (sp.g[j + 1] - sp.g[j]);
#pragma unroll
  for (int j = 0; j < 10; ++j) sp.d2[j] = 1.0f / (sp.g[j + 2] - sp.g[j]);
#pragma unroll
  for (int j = 0; j < 9; ++j) sp.d3[j] = 1.0f / (sp.g[j + 3] - sp.g[j]);
}
__device__ __forceinline__ void expand_one(float v, const Spl& sp, u16* dst) {
  float Bv[11];
#pragma unroll
  for (int j = 0; j < 11; ++j) Bv[j] = (v >= sp.g[j] && v < sp.g[j + 1]) ? 1.0f : 0.0f;
#pragma unroll
  for (int j = 0; j < 10; ++j)
    Bv[j] = (v - sp.g[j]) * sp.d1[j] * Bv[j] + (sp.g[j + 2] - v) * sp.d1[j + 1] * Bv[j + 1];
#pragma unroll
  for (int j = 0; j < 9; ++j)
    Bv[j] = (v - sp.g[j]) * sp.d2[j] * Bv[j] + (sp.g[j + 3] - v) * sp.d2[j + 1] * Bv[j + 1];
#pragma unroll
  for (int j = 0; j < 8; ++j)
    Bv[j] = (v - sp.g[j]) * sp.d3[j] * Bv[j] + (sp.g[j + 4] - v) * sp.d3[j + 1] * Bv[j + 1];
  dst[0] = f2bf_rne(v / (1.0f + __expf(-v)));  // silu
#pragma unroll
  for (int k = 0; k < 8; ++k) dst[1 + k] = f2bf_rne(Bv[k]);
}

// ---- big-tile split-K MFMA GEMM ----
// Cpart[s][M][N] += A[M,K']@B[N,K']^T chunk s.  BM=BN=128, 4 waves (2x2),
// wave-tile 64x64 (acc 4x f32x16), BK=64, 2-buf LDS (64KB -> 2 blocks/CU).
// 2-phase loop: stage(next) -> ds_read(cur) -> MFMA -> vmcnt(0) -> barrier.
// NREG==3: K'=3*K regions hh/hl/lh (split-precision bf16x3, K=1024).
template <int NREG>
__global__ __launch_bounds__(256, 2) void gemm_bigtile(
    const u16* __restrict__ A0, const u16* __restrict__ A1,
    const u16* __restrict__ B0, const u16* __restrict__ B1,
    float* __restrict__ Cpart, int M, int N, int K, int S, int steps) {
  constexpr int ASZ = 128 * 64;  // u16
  constexpr int BUF_U16 = 2 * ASZ;
  __shared__ __align__(16) u16 smu[2 * BUF_U16];  // 64 KB

  const int tid = threadIdx.x;
  const int lane = tid & 63;
  const int wid = tid >> 6;

  const int bid = blockIdx.x;
  const int t = bid / S;
  const int s = bid - t * S;
  const int ntn = N >> 7;
  const int ntiles = (M >> 7) * ntn;
  const int tsw = (t & 7) * (ntiles >> 3) + (t >> 3);  // XCD swizzle (ntiles%8==0)
  const int tm = (tsw / ntn) << 7;
  const int tn = (tsw % ntn) << 7;

  const size_t gAoff = (size_t)tm * K;
  const size_t gBoff = (size_t)tn * K;

  // chunk c: row=c>>3, slot=c&7; slot sources logical k-group slot^(row&7)
  auto srcOff = [&](int c) -> size_t {
    int r = c >> 3, sl = c & 7;
    return (size_t)r * K + (size_t)(((sl ^ (r & 7)) & 7) << 3);
  };
  size_t aSrc[4], bSrc[4];
#pragma unroll
  for (int c = 0; c < 4; ++c) aSrc[c] = srcOff(tid + c * 256);
#pragma unroll
  for (int c = 0; c < 4; ++c) bSrc[c] = srcOff(tid + c * 256);

  const int wm = (wid >> 1) * 64;
  const int wn = (wid & 1) * 64;
  const int lr = lane & 31;
  const int khf = lane >> 5;

  // swizzled LDS read offsets: row*64 + ((ks*2+khf)^(row&7))*8
  int offA[2][4], offB[2][4];
#pragma unroll
  for (int mb = 0; mb < 2; ++mb) {
    int row = wm + mb * 32 + lr;
#pragma unroll
    for (int ks = 0; ks < 4; ++ks)
      offA[mb][ks] = row * 64 + ((((ks * 2 + khf) ^ (row & 7)) & 7) << 3);
  }
#pragma unroll
  for (int nb = 0; nb < 2; ++nb) {
    int row = wn + nb * 32 + lr;
#pragma unroll
    for (int ks = 0; ks < 4; ++ks)
      offB[nb][ks] = row * 64 + ((((ks * 2 + khf) ^ (row & 7)) & 7) << 3);
  }

  auto stage = [&](int buf, int gstep) {
    const u16 *Ab, *Bb;
    int kk;
    if constexpr (NREG == 3) {
      int reg = gstep >> 4;  // K=1024 -> 16 BK-64 steps per region
      kk = (gstep & 15) << 6;
      Ab = (reg == 2) ? A1 : A0;
      Bb = (reg == 1) ? B1 : B0;
    } else {
      kk = gstep << 6;
      Ab = A0;
      Bb = B0;
    }
    u16* sb = smu + buf * BUF_U16;
#pragma unroll
    for (int c = 0; c < 4; ++c)
      gload16(Ab + gAoff + aSrc[c] + kk, sb + (c * 256 + wid * 64) * 8);
#pragma unroll
    for (int c = 0; c < 4; ++c)
      gload16(Bb + gBoff + bSrc[c] + kk, sb + ASZ + (c * 256 + wid * 64) * 8);
  };

  f32x16 acc[2][2] = {};
  const int gbase = s * steps;

  stage(0, gbase);
  asm volatile("s_waitcnt vmcnt(0)" ::: "memory");
  __builtin_amdgcn_sched_barrier(0);
  __builtin_amdgcn_s_barrier();

  int cur = 0;
  for (int i = 0; i < steps; ++i) {
    if (i + 1 < steps) stage(cur ^ 1, gbase + i + 1);

    const u16* sb = smu + cur * BUF_U16;
    bf16x8 af[2][4], bf[2][4];
#pragma unroll
    for (int mb = 0; mb < 2; ++mb)
#pragma unroll
      for (int ks = 0; ks < 4; ++ks) af[mb][ks] = *(const bf16x8*)(sb + offA[mb][ks]);
#pragma unroll
    for (int nb = 0; nb < 2; ++nb)
#pragma unroll
      for (int ks = 0; ks < 4; ++ks) bf[nb][ks] = *(const bf16x8*)(sb + ASZ + offB[nb][ks]);

#pragma unroll
    for (int ks = 0; ks < 4; ++ks)
#pragma unroll
      for (int mb = 0; mb < 2; ++mb)
#pragma unroll
        for (int nb = 0; nb < 2; ++nb)
          acc[mb][nb] = __builtin_amdgcn_mfma_f32_32x32x16_bf16(af[mb][ks], bf[nb][ks],
                                                                acc[mb][nb], 0, 0, 0);

    asm volatile("s_waitcnt vmcnt(0)" ::: "memory");  // drain my stage before barrier
    __builtin_amdgcn_sched_barrier(0);
    __builtin_amdgcn_s_barrier();
    cur ^= 1;
  }

  // C/D layout (m74/m101): col = lane&31, row = (r&3) + 8*(r>>2) + 4*(lane>>5)
  float* Cp = Cpart + (size_t)s * M * N;
#pragma unroll
  for (int mb = 0; mb < 2; ++mb)
#pragma unroll
    for (int nb = 0; nb < 2; ++nb) {
      const f32x16 a = acc[mb][nb];
      const int cbase = tn + wn + nb * 32 + lr;
#pragma unroll
      for (int r = 0; r < 16; ++r) {
        int row = tm + wm + mb * 32 + (r & 3) + 8 * (r >> 2) + 4 * khf;
        Cp[(size_t)row * N + cbase] = a[r];
      }
    }
}

// ---- reduce split-K partials (+bias) -> spline-expand -> F bf16 ----
__global__ void reduce_expand_kernel(const float* __restrict__ P, const float* __restrict__ bias,
                                     const float* __restrict__ grid, u16* __restrict__ Fhi,
                                     int MN, int N, int S) {
  int idx = blockIdx.x * blockDim.x + threadIdx.x;
  if (idx >= MN) return;
  float v = 0.0f;
  for (int s = 0; s < S; ++s) v += P[(size_t)s * MN + idx];
  if (bias) v += bias[idx & (N - 1)];
  Spl sp;
  spl_init(grid, sp);
  expand_one(v, sp, Fhi + (size_t)idx * 9);
}

// ---- reduce split-K partials -> f32 out (final layer) ----
__global__ void reduce_kernel(const float* __restrict__ P, float* __restrict__ outp,
                              int MN, int S) {
  int i = blockIdx.x * blockDim.x + threadIdx.x;
  if (i >= MN) return;
  float v = 0.0f;
  for (int s = 0; s < S; ++s) v += P[(size_t)s * MN + i];
  outp[i] = v;
}

extern "C" void kernel_launch(void* const* d_in, const int* in_sizes, int n_in,
                              void* d_out, int out_size, void* d_ws, size_t ws_size,
                              hipStream_t stream) {
  (void)in_sizes; (void)n_in; (void)out_size; (void)ws_size;
  const float* x     = (const float*)d_in[0];   // 4096x1024
  const float* W1    = (const float*)d_in[1];   // 256x1024
  const float* b1    = (const float*)d_in[2];   // 256
  const float* grid1 = (const float*)d_in[3];   // 256x12 (rows identical)
  const float* coef1 = (const float*)d_in[4];   // 256x256x8
  const float* sb1   = (const float*)d_in[5];
  const float* sp1   = (const float*)d_in[6];
  const float* mask1 = (const float*)d_in[7];
  const float* grid2 = (const float*)d_in[8];
  const float* coef2 = (const float*)d_in[9];   // 256x128x8
  const float* sb2   = (const float*)d_in[10];
  const float* sp2   = (const float*)d_in[11];
  const float* mask2 = (const float*)d_in[12];
  float* outp = (float*)d_out;

  char* ws = (char*)d_ws;
  size_t off = 0;
  auto alloc = [&](size_t bytes) {
    char* p = ws + off;
    off += (bytes + 255) & ~(size_t)255;
    return (void*)p;
  };
  u16* xs_hi  = (u16*)alloc((size_t)4096 * 1024 * 2);
  u16* xs_lo  = (u16*)alloc((size_t)4096 * 1024 * 2);
  u16* w1_hi  = (u16*)alloc((size_t)256 * 1024 * 2);
  u16* w1_lo  = (u16*)alloc((size_t)256 * 1024 * 2);
  u16* wc1    = (u16*)alloc((size_t)256 * K2L * 2);
  u16* wc2    = (u16*)alloc((size_t)128 * K2L * 2);
  u16* F1     = (u16*)alloc((size_t)4096 * K2L * 2);
  u16* F2     = (u16*)alloc((size_t)4096 * K2L * 2);
  float* part = (float*)alloc((size_t)8 * 4096 * 256 * 4);  // max: L1 S=8

  // merged prep
  prep_kernel<<<7808, 256, 0, stream>>>(x, W1, coef1, sb1, sp1, mask1,
                                        coef2, sb2, sp2, mask2,
                                        xs_hi, xs_lo, w1_hi, w1_lo, wc1, wc2);

  // L1: h1-partials = x @ W1^T (bf16x3, K'=3072); 64 tiles x S=8 = 512 blocks, 6 steps
  gemm_bigtile<3><<<512, 256, 0, stream>>>(xs_hi, xs_lo, w1_hi, w1_lo, part,
                                           4096, 256, 1024, 8, 6);
  reduce_expand_kernel<<<4096, 256, 0, stream>>>(part, b1, grid1, F1, 4096 * 256, 256, 8);

  // L2: h2-partials = F1 @ Wc1^T (K=2304); 64 tiles x S=6 = 384 blocks, 6 steps
  gemm_bigtile<1><<<384, 256, 0, stream>>>(F1, nullptr, wc1, nullptr, part,
                                           4096, 256, 2304, 6, 6);
  reduce_expand_kernel<<<4096, 256, 0, stream>>>(part, nullptr, grid2, F2, 4096 * 256, 256, 6);

  // L3: out-partials = F2 @ Wc2^T (K=2304, N=128); 32 tiles x S=6 = 192 blocks, 6 steps
  gemm_bigtile<1><<<192, 256, 0, stream>>>(F2, nullptr, wc2, nullptr, part,
                                           4096, 128, 2304, 6, 6);
  reduce_kernel<<<2048, 256, 0, stream>>>(part, outp, 4096 * 128, 6);
}